// Round 1
// baseline (156.463 us; speedup 1.0000x reference)
//
#include <hip/hip_runtime.h>
#include <math.h>

// Problem: SphericalHarmonicTransform, L=8, RCUT=5, N=4194304 points.
// out[81] = sum over points of (modified) solid harmonic terms.
// Compute-bound: ~550 fp32 ops/point vs 12 B/point of HBM traffic.

#define NL 8               // L
#define NACC 45            // (l,m) pairs, m<=l, l<=8

__device__ __forceinline__ float waveReduce(float v) {
    v += __shfl_down(v, 32);
    v += __shfl_down(v, 16);
    v += __shfl_down(v, 8);
    v += __shfl_down(v, 4);
    v += __shfl_down(v, 2);
    v += __shfl_down(v, 1);
    return v;
}

__global__ __launch_bounds__(256, 2)
void sht_main(const float* __restrict__ pos, float* __restrict__ ws, int n) {
    // Factorials (exact in fp32 up to 8!)
    const float FACT[9] = {1.f, 1.f, 2.f, 6.f, 24.f, 120.f, 720.f, 5040.f, 40320.f};

    float accr[NACC];
    float acci[NACC];
#pragma unroll
    for (int i = 0; i < NACC; ++i) { accr[i] = 0.f; acci[i] = 0.f; }

    const int tid = blockIdx.x * blockDim.x + threadIdx.x;
    const int stride = gridDim.x * blockDim.x;

    for (int i = tid; i < n; i += stride) {
        const float x = pos[3 * i + 0];
        const float y = pos[3 * i + 1];
        const float z = pos[3 * i + 2];

        const float r2 = x * x + y * y + z * z;
        const float norm = sqrtf(r2);
        // cut = 0.5*(cos(norm*pi/RCUT)+1), zeroed past RCUT and at norm==0
        float cut = 0.5f * (__cosf(norm * 0.6283185307179586f) + 1.0f);
        cut = (norm > 5.0f) ? 0.0f : cut;
        cut = (norm > 0.0f) ? cut : 0.0f;
        const float safe = (norm > 0.0f) ? norm : 1.0f;
        const float inv = __builtin_amdgcn_rcpf(safe);
        const float x0c = z * cut;  // fold cutoff into x0

        const float xpr = -0.5f * x, xpi = -0.5f * y;
        const float xmr = 0.5f * x, xmi = -0.5f * y;

        // powcmplx replication:
        //  n=0 -> (1,0); n=1 -> (z); n=2 -> special (r^2-i^2, 2ri);
        //  n>=3 -> "buggy" chain: r' = ar*r - ai*im; im' = ar*im + ai*r'  (uses NEW r)
        float z1r[9], z1i[9], z2r[9], z2i[9];
        z1r[0] = 1.f; z1i[0] = 0.f; z1r[1] = xpr; z1i[1] = xpi;
        z2r[0] = 1.f; z2i[0] = 0.f; z2r[1] = xmr; z2i[1] = xmi;
        z1r[2] = xpr * xpr - xpi * xpi; z1i[2] = 2.f * xpr * xpi;
        z2r[2] = xmr * xmr - xmi * xmi; z2i[2] = 2.f * xmr * xmi;
        {
            float br = xpr, bi = xpi;
#pragma unroll
            for (int k = 2; k <= NL; ++k) {
                const float nr = xpr * br - xpi * bi;
                const float ni = xpr * bi + xpi * nr;   // buggy: uses nr
                br = nr; bi = ni;
                if (k >= 3) { z1r[k] = br; z1i[k] = bi; }
            }
        }
        {
            float br = xmr, bi = xmi;
#pragma unroll
            for (int k = 2; k <= NL; ++k) {
                const float nr = xmr * br - xmi * bi;
                const float ni = xmr * bi + xmi * nr;   // buggy: uses nr
                br = nr; bi = ni;
                if (k >= 3) { z2r[k] = br; z2i[k] = bi; }
            }
        }

        // T(p,q) for q<=p, p+q<=8, times x0c. (zr = z1r^2 - z2i^2 as in ref!)
        float Xr[9][9], Xi[9][9];
#pragma unroll
        for (int p = 0; p <= NL; ++p) {
#pragma unroll
            for (int q = 0; q <= NL; ++q) {
                if (q <= p && p + q <= NL) {
                    const float tr = z1r[p] * z1r[p] - z2i[q] * z2i[q];
                    const float ti = z1r[p] * z2i[q] + z1i[p] * z2r[q];
                    Xr[p][q] = tr * x0c;
                    Xi[p][q] = ti * x0c;
                }
            }
        }

        // g_l = inv^l (cut already folded into x0c; k_l,f,fac folded into finalize)
        float g[9];
        g[0] = 1.f;
#pragma unroll
        for (int l = 1; l <= NL; ++l) g[l] = g[l - 1] * inv;

        // accumulate: acc(l,m) += g_l * sum_p c(p,q,s) * X(p, p-m)
#pragma unroll
        for (int l = 0; l <= NL; ++l) {
#pragma unroll
            for (int m = 0; m <= NL; ++m) {
                if (m <= l) {
                    float sr = 0.f, si = 0.f;
#pragma unroll
                    for (int p = 0; p <= NL; ++p) {
                        if (p >= m && (2 * p - m) <= l) {
                            const int q = p - m;
                            const int s = l - p - q;
                            const float c = 1.0f / (FACT[p] * FACT[q] * FACT[s]);
                            sr = fmaf(Xr[p][q], c, sr);
                            si = fmaf(Xi[p][q], c, si);
                        }
                    }
                    const int ai = l * (l + 1) / 2 + m;
                    accr[ai] = fmaf(sr, g[l], accr[ai]);
                    if (m > 0) acci[ai] = fmaf(si, g[l], acci[ai]);
                }
            }
        }
    }

    // ---- reduction: wave shuffle -> LDS across 4 waves -> atomics ----
    __shared__ float red[81][5];   // [out slot][wave], padded stride
    const int lane = threadIdx.x & 63;
    const int wave = threadIdx.x >> 6;

#pragma unroll
    for (int l = 0; l <= NL; ++l) {
#pragma unroll
        for (int m = 0; m <= NL; ++m) {
            if (m <= l) {
                const int ai = l * (l + 1) / 2 + m;
                float vr = waveReduce(accr[ai]);
                if (lane == 0) red[l * l + l + m][wave] = vr;
                if (m > 0) {
                    float vi = waveReduce(acci[ai]);
                    if (lane == 0) red[l * l + l - m][wave] = vi;
                }
            }
        }
    }
    __syncthreads();

    if ((int)threadIdx.x < 81) {
        float s = 0.f;
#pragma unroll
        for (int w = 0; w < 4; ++w) s += red[threadIdx.x][w];
        atomicAdd(&ws[threadIdx.x], s);
    }
}

__device__ double dfact(int nn) {
    double r = 1.0;
    for (int i = 2; i <= nn; ++i) r *= (double)i;
    return r;
}

__global__ void sht_finalize(const float* __restrict__ ws, float* __restrict__ out) {
    const int j = threadIdx.x;
    if (j < 81) {
        int l = 0;
        while ((l + 1) * (l + 1) <= j) ++l;
        const int M = j - l * l - l;
        const int m = (M < 0) ? -M : M;
        // f = sqrt((l+m)!(l-m)!); k_l = sqrt((2l+1)/(4*3.14159))  (ref uses PI=3.14159 here)
        double sc = sqrt(dfact(l + m) * dfact(l - m)) *
                    sqrt((double)(2 * l + 1) / (4.0 * 3.14159));
        if (m > 0) sc *= sqrt(2.0) * ((m & 1) ? -1.0 : 1.0);
        out[j] = (float)((double)ws[j] * sc);
    }
}

extern "C" void kernel_launch(void* const* d_in, const int* in_sizes, int n_in,
                              void* d_out, int out_size, void* d_ws, size_t ws_size,
                              hipStream_t stream) {
    const float* pos = (const float*)d_in[0];
    const int npts = in_sizes[0] / 3;
    float* ws = (float*)d_ws;
    float* out = (float*)d_out;

    hipMemsetAsync(d_ws, 0, 81 * sizeof(float), stream);
    sht_main<<<512, 256, 0, stream>>>(pos, ws, npts);
    sht_finalize<<<1, 128, 0, stream>>>(ws, out);
}